// Round 1
// 903.959 us; speedup vs baseline: 1.2959x; 1.2959x over previous
//
#include <hip/hip_runtime.h>

typedef _Float16 half8 __attribute__((ext_vector_type(8)));
typedef float floatx4 __attribute__((ext_vector_type(4)));

// LDS layout helper: rows of 32 fp16 (one BK=32 slice), 4 chunks of 8, XOR-swizzled
// so ds_read_b128 fragment reads are ~conflict-free.
__device__ __forceinline__ int lds_off(int row, int chunk) {
    return row * 32 + ((chunk ^ (row & 3)) << 3);
}

// C = A @ B^T (both row-major [rows, K]) with optional fp32->fp16 conversion during
// staging. 128x128 tile, 4 waves, BK=32, mfma_f32_16x16x32_f16.
// OUT_MODE 0: fp16 head-split [bh][l][d]   (QK projection)
// OUT_MODE 1: fp16 head-split transposed [bh][d][l]  (V projection)
// OUT_MODE 2: fp32 row-major ldc=1024 (+bias)        (output projection)
template<bool A_F32, bool B_F32, int OUT_MODE>
__global__ __launch_bounds__(256) void gemm128(
    const void* __restrict__ Ap, int lda, long sAz,
    const void* __restrict__ Bp, int ldb, long sBz,
    const float* __restrict__ bias, float scale,
    void* __restrict__ Cp, long sCz, int K)
{
    __shared__ __align__(16) _Float16 sA[128 * 32];
    __shared__ __align__(16) _Float16 sB[128 * 32];

    const int t = threadIdx.x;
    const int tileN = blockIdx.x * 128;
    const int tileM = blockIdx.y * 128;
    const int z = blockIdx.z;

    const int srow = t >> 1, shalf = t & 1, c0 = shalf * 2;
    const int lane = t & 63, wave = t >> 6;
    const int wm = (wave >> 1) * 64, wn = (wave & 1) * 64;
    const int l15 = lane & 15, quad = lane >> 4;

    const char* Abase = (const char*)Ap + (long)z * sAz * (A_F32 ? 4 : 2);
    const char* Bbase = (const char*)Bp + (long)z * sBz * (B_F32 ? 4 : 2);

    floatx4 acc[4][4];
#pragma unroll
    for (int i = 0; i < 4; i++)
#pragma unroll
        for (int j = 0; j < 4; j++)
            acc[i][j] = (floatx4){0.f, 0.f, 0.f, 0.f};

    for (int k0 = 0; k0 < K; k0 += 32) {
        __syncthreads();
        // ---- stage A tile (128 x 32) ----
        if constexpr (A_F32) {
            const float* src = (const float*)Abase + (long)(tileM + srow) * lda + k0 + shalf * 16;
            float fx[16];
            *(float4*)(fx + 0)  = *(const float4*)(src + 0);
            *(float4*)(fx + 4)  = *(const float4*)(src + 4);
            *(float4*)(fx + 8)  = *(const float4*)(src + 8);
            *(float4*)(fx + 12) = *(const float4*)(src + 12);
            half8 h0, h1;
#pragma unroll
            for (int i = 0; i < 8; i++) { h0[i] = (_Float16)fx[i]; h1[i] = (_Float16)fx[8 + i]; }
            *(half8*)&sA[lds_off(srow, c0)]     = h0;
            *(half8*)&sA[lds_off(srow, c0 + 1)] = h1;
        } else {
            const _Float16* src = (const _Float16*)Abase + (long)(tileM + srow) * lda + k0 + shalf * 16;
            *(half8*)&sA[lds_off(srow, c0)]     = *(const half8*)(src);
            *(half8*)&sA[lds_off(srow, c0 + 1)] = *(const half8*)(src + 8);
        }
        // ---- stage B tile (128 x 32) ----
        if constexpr (B_F32) {
            const float* src = (const float*)Bbase + (long)(tileN + srow) * ldb + k0 + shalf * 16;
            float fx[16];
            *(float4*)(fx + 0)  = *(const float4*)(src + 0);
            *(float4*)(fx + 4)  = *(const float4*)(src + 4);
            *(float4*)(fx + 8)  = *(const float4*)(src + 8);
            *(float4*)(fx + 12) = *(const float4*)(src + 12);
            half8 h0, h1;
#pragma unroll
            for (int i = 0; i < 8; i++) { h0[i] = (_Float16)fx[i]; h1[i] = (_Float16)fx[8 + i]; }
            *(half8*)&sB[lds_off(srow, c0)]     = h0;
            *(half8*)&sB[lds_off(srow, c0 + 1)] = h1;
        } else {
            const _Float16* src = (const _Float16*)Bbase + (long)(tileN + srow) * ldb + k0 + shalf * 16;
            *(half8*)&sB[lds_off(srow, c0)]     = *(const half8*)(src);
            *(half8*)&sB[lds_off(srow, c0 + 1)] = *(const half8*)(src + 8);
        }
        __syncthreads();

        half8 af[4], bf[4];
#pragma unroll
        for (int i = 0; i < 4; i++) af[i] = *(const half8*)&sA[lds_off(wm + i * 16 + l15, quad)];
#pragma unroll
        for (int j = 0; j < 4; j++) bf[j] = *(const half8*)&sB[lds_off(wn + j * 16 + l15, quad)];
#pragma unroll
        for (int i = 0; i < 4; i++)
#pragma unroll
            for (int j = 0; j < 4; j++)
                acc[i][j] = __builtin_amdgcn_mfma_f32_16x16x32_f16(af[i], bf[j], acc[i][j], 0, 0, 0);
    }

    // ---- epilogue ----
#pragma unroll
    for (int i = 0; i < 4; i++) {
#pragma unroll
        for (int j = 0; j < 4; j++) {
#pragma unroll
            for (int r = 0; r < 4; r++) {
                const int row = tileM + wm + i * 16 + quad * 4 + r;
                const int col = tileN + wn + j * 16 + l15;
                float v = acc[i][j][r] * scale;
                if (bias) v += bias[col];
                if constexpr (OUT_MODE == 0) {
                    _Float16* dst = (_Float16*)Cp;
                    dst[(long)(((row >> 11) << 4) + (col >> 6)) * 131072 + (long)(row & 2047) * 64 + (col & 63)] = (_Float16)v;
                } else if constexpr (OUT_MODE == 1) {
                    _Float16* dst = (_Float16*)Cp;
                    dst[(long)(((row >> 11) << 4) + (col >> 6)) * 131072 + (long)(col & 63) * 2048 + (row & 2047)] = (_Float16)v;
                } else {
                    float* dst = (float*)Cp;
                    dst[(long)row * 1024 + col] = v;
                }
            }
        }
    }
}

// Fused attention: per (b,h) and 128-query-row block, two-pass flash-style.
// Pass 1: S = Q K^T /8 tile-by-tile (K tiles of 128 keys), exact online row max m
// and sum l (no global traffic except tiny K reads, L2-resident).
// Pass 2: recompute S, write normalized P = exp(s-m)/l once to weights (fp32,
// nontemporal), stash P as fp16 in swizzled LDS, accumulate Z += P @ Vt^T via MFMA.
// Q fragments live in registers for the whole kernel.
__global__ __launch_bounds__(256, 2) void attn_fused(
    const _Float16* __restrict__ Q,   // [32][2048][64]
    const _Float16* __restrict__ K,   // [32][2048][64]
    const _Float16* __restrict__ Vt,  // [32][64][2048]
    float* __restrict__ W,            // [32][2048][2048] (weights output)
    _Float16* __restrict__ Z)         // [4096][1024]  (b,l,h,d)
{
    __shared__ __align__(16) _Float16 sK[128 * 64];   // K tile  [128 key][64 d]
    __shared__ __align__(16) _Float16 sV[64 * 128];   // Vt tile [64 d][128 key]
    __shared__ __align__(16) _Float16 sP[128 * 128];  // P tile  [128 q][128 key]

    const int t = threadIdx.x;
    const int tileM = blockIdx.x * 128;
    const int bh = blockIdx.y;
    const int lane = t & 63, wave = t >> 6;
    const int l15 = lane & 15, quad = lane >> 4;
    const int wm = wave * 32;

    const _Float16* Qb = Q + (long)bh * 131072;
    const _Float16* Kb = K + (long)bh * 131072;
    const _Float16* Vb = Vt + (long)bh * 131072;
    float* Wb = W + (long)bh * 4194304;

    const int krow = t >> 1, khalf = t & 1;   // K staging: 2 threads/row, 64B each
    const int vrow = t >> 2, vq = t & 3;      // V staging: 4 threads/row

    // Q fragments (persistent): lane holds Q[row=wm+i*16+l15][k=kk*32+quad*8+e]
    half8 qf[2][2];
#pragma unroll
    for (int i = 0; i < 2; i++)
#pragma unroll
        for (int kk = 0; kk < 2; kk++)
            qf[i][kk] = *(const half8*)(Qb + (long)(tileM + wm + i * 16 + l15) * 64 + kk * 32 + quad * 8);

    float m[2][4], l[2][4];
#pragma unroll
    for (int i = 0; i < 2; i++)
#pragma unroll
        for (int r = 0; r < 4; r++) { m[i][r] = -__builtin_inff(); l[i][r] = 0.f; }

    // ---------------- pass 1: row stats ----------------
    for (int kv = 0; kv < 2048; kv += 128) {
        __syncthreads();
        {
            const _Float16* src = Kb + (long)(kv + krow) * 64 + khalf * 32;
#pragma unroll
            for (int c = 0; c < 4; c++)
                *(half8*)&sK[krow * 64 + ((((khalf * 4 + c)) ^ (krow & 7)) << 3)] = *(const half8*)(src + c * 8);
        }
        __syncthreads();

        floatx4 acc[2][8];
#pragma unroll
        for (int i = 0; i < 2; i++)
#pragma unroll
            for (int j = 0; j < 8; j++) acc[i][j] = (floatx4){0.f, 0.f, 0.f, 0.f};

#pragma unroll
        for (int kk = 0; kk < 2; kk++) {
#pragma unroll
            for (int j = 0; j < 8; j++) {
                const int row = j * 16 + l15;
                half8 bf = *(const half8*)&sK[row * 64 + (((kk * 4 + quad) ^ (row & 7)) << 3)];
                acc[0][j] = __builtin_amdgcn_mfma_f32_16x16x32_f16(qf[0][kk], bf, acc[0][j], 0, 0, 0);
                acc[1][j] = __builtin_amdgcn_mfma_f32_16x16x32_f16(qf[1][kk], bf, acc[1][j], 0, 0, 0);
            }
        }

#pragma unroll
        for (int i = 0; i < 2; i++)
#pragma unroll
            for (int r = 0; r < 4; r++) {
                float tmax = acc[i][0][r];
#pragma unroll
                for (int j = 1; j < 8; j++) tmax = fmaxf(tmax, acc[i][j][r]);
#pragma unroll
                for (int off = 1; off < 16; off <<= 1) tmax = fmaxf(tmax, __shfl_xor(tmax, off));
                const float mn = fmaxf(m[i][r], tmax * 0.125f);
                const float corr = __expf(m[i][r] - mn);
                float ts = 0.f;
#pragma unroll
                for (int j = 0; j < 8; j++) ts += __expf(acc[i][j][r] * 0.125f - mn);
#pragma unroll
                for (int off = 1; off < 16; off <<= 1) ts += __shfl_xor(ts, off);
                l[i][r] = l[i][r] * corr + ts;
                m[i][r] = mn;
            }
    }

    // invert sums once
#pragma unroll
    for (int i = 0; i < 2; i++)
#pragma unroll
        for (int r = 0; r < 4; r++) l[i][r] = 1.f / l[i][r];

    floatx4 accz[2][4];
#pragma unroll
    for (int i = 0; i < 2; i++)
#pragma unroll
        for (int j = 0; j < 4; j++) accz[i][j] = (floatx4){0.f, 0.f, 0.f, 0.f};

    // ---------------- pass 2: P write + PV ----------------
    for (int kv = 0; kv < 2048; kv += 128) {
        __syncthreads();
        {
            const _Float16* src = Kb + (long)(kv + krow) * 64 + khalf * 32;
#pragma unroll
            for (int c = 0; c < 4; c++)
                *(half8*)&sK[krow * 64 + ((((khalf * 4 + c)) ^ (krow & 7)) << 3)] = *(const half8*)(src + c * 8);
            const _Float16* vsrc = Vb + (long)vrow * 2048 + kv;
#pragma unroll
            for (int c = 0; c < 4; c++) {
                const int ch = vq + c * 4;
                *(half8*)&sV[vrow * 128 + ((ch ^ (vrow & 15)) << 3)] = *(const half8*)(vsrc + ch * 8);
            }
        }
        __syncthreads();

        floatx4 acc[2][8];
#pragma unroll
        for (int i = 0; i < 2; i++)
#pragma unroll
            for (int j = 0; j < 8; j++) acc[i][j] = (floatx4){0.f, 0.f, 0.f, 0.f};

#pragma unroll
        for (int kk = 0; kk < 2; kk++) {
#pragma unroll
            for (int j = 0; j < 8; j++) {
                const int row = j * 16 + l15;
                half8 bf = *(const half8*)&sK[row * 64 + (((kk * 4 + quad) ^ (row & 7)) << 3)];
                acc[0][j] = __builtin_amdgcn_mfma_f32_16x16x32_f16(qf[0][kk], bf, acc[0][j], 0, 0, 0);
                acc[1][j] = __builtin_amdgcn_mfma_f32_16x16x32_f16(qf[1][kk], bf, acc[1][j], 0, 0, 0);
            }
        }

        // normalize, write weights (fp32, exactly once), stash fp16 P into LDS
#pragma unroll
        for (int i = 0; i < 2; i++) {
#pragma unroll
            for (int r = 0; r < 4; r++) {
                const int q = wm + i * 16 + quad * 4 + r;
                float* wr = Wb + (long)(tileM + q) * 2048 + kv + l15;
                _Float16* sprow = &sP[q * 128 + (l15 & 7)];
                const int qx = q & 15;
                const int hi = l15 >> 3;
#pragma unroll
                for (int j = 0; j < 8; j++) {
                    const float p = __expf(acc[i][j][r] * 0.125f - m[i][r]) * l[i][r];
                    __builtin_nontemporal_store(p, wr + j * 16);
                    sprow[((j * 2 + hi) ^ qx) << 3] = (_Float16)p;
                }
            }
        }
        __syncthreads();

        // Z += P @ Vt^T  (k-dim = 128 keys of this tile)
#pragma unroll
        for (int kk = 0; kk < 4; kk++) {
            half8 pf[2];
#pragma unroll
            for (int i = 0; i < 2; i++) {
                const int q = wm + i * 16 + l15;
                pf[i] = *(const half8*)&sP[q * 128 + (((kk * 4 + quad) ^ (q & 15)) << 3)];
            }
#pragma unroll
            for (int j = 0; j < 4; j++) {
                const int d = j * 16 + l15;
                half8 vf = *(const half8*)&sV[d * 128 + (((kk * 4 + quad) ^ (d & 15)) << 3)];
                accz[0][j] = __builtin_amdgcn_mfma_f32_16x16x32_f16(pf[0], vf, accz[0][j], 0, 0, 0);
                accz[1][j] = __builtin_amdgcn_mfma_f32_16x16x32_f16(pf[1], vf, accz[1][j], 0, 0, 0);
            }
        }
    }

    // ---- epilogue: Z to fp16 workspace [b*2048+l][h*64+d] ----
    const int bb = bh >> 4, hd = bh & 15;
#pragma unroll
    for (int i = 0; i < 2; i++)
#pragma unroll
        for (int j = 0; j < 4; j++)
#pragma unroll
            for (int r = 0; r < 4; r++)
                Z[(long)(bb * 2048 + tileM + wm + i * 16 + quad * 4 + r) * 1024 + hd * 64 + j * 16 + l15] =
                    (_Float16)accz[i][j][r];
}

extern "C" void kernel_launch(void* const* d_in, const int* in_sizes, int n_in,
                              void* d_out, int out_size, void* d_ws, size_t ws_size,
                              hipStream_t stream) {
    (void)in_sizes; (void)n_in; (void)out_size; (void)ws_size;
    const float* query = (const float*)d_in[0];
    const float* key   = (const float*)d_in[1];
    const float* value = (const float*)d_in[2];
    const float* Wq = (const float*)d_in[3];
    const float* bq = (const float*)d_in[4];
    const float* Wk = (const float*)d_in[5];
    const float* bk = (const float*)d_in[6];
    const float* Wv = (const float*)d_in[7];
    const float* bv = (const float*)d_in[8];
    const float* Wo = (const float*)d_in[9];
    const float* bo = (const float*)d_in[10];

    _Float16* wsQ  = (_Float16*)d_ws;        // [32][2048][64]
    _Float16* wsK  = wsQ + 4194304;          // [32][2048][64]
    _Float16* wsVt = wsK + 4194304;          // [32][64][2048]
    _Float16* wsZ  = wsVt + 4194304;         // [4096][1024]

    float* outF = (float*)d_out;             // [4096][1024]
    float* Wgt  = outF + 4194304;            // [32][2048][2048]

    dim3 blk(256);
    // Q/K/V projections (fp32 inputs converted during staging)
    gemm128<true, true, 0><<<dim3(8, 32, 1), blk, 0, stream>>>(query, 1024, 0, Wq, 1024, 0, bq, 1.0f, wsQ, 0, 1024);
    gemm128<true, true, 0><<<dim3(8, 32, 1), blk, 0, stream>>>(key,   1024, 0, Wk, 1024, 0, bk, 1.0f, wsK, 0, 1024);
    gemm128<true, true, 1><<<dim3(8, 32, 1), blk, 0, stream>>>(value, 1024, 0, Wv, 1024, 0, bv, 1.0f, wsVt, 0, 1024);
    // Fused scores + softmax + AV: writes weights once, Z to workspace
    attn_fused<<<dim3(16, 32), blk, 0, stream>>>(wsQ, wsK, wsVt, Wgt, wsZ);
    // out = Z Wo^T + bo
    gemm128<false, true, 2><<<dim3(8, 32, 1), blk, 0, stream>>>(wsZ, 1024, 0, Wo, 1024, 0, bo, 1.0f, outF, 0, 1024);
}

// Round 2
// 850.840 us; speedup vs baseline: 1.3768x; 1.0624x over previous
//
#include <hip/hip_runtime.h>

typedef _Float16 half8 __attribute__((ext_vector_type(8)));
typedef _Float16 half4 __attribute__((ext_vector_type(4)));
typedef float floatx4 __attribute__((ext_vector_type(4)));

// LDS layout helper: rows of 32 fp16 (one BK=32 slice), 4 chunks of 8, XOR-swizzled
// so ds_read_b128 fragment reads are ~conflict-free.
__device__ __forceinline__ int lds_off(int row, int chunk) {
    return row * 32 + ((chunk ^ (row & 3)) << 3);
}

__device__ __forceinline__ void ld16f(float* d, const float* s) {
    *(float4*)(d + 0)  = *(const float4*)(s + 0);
    *(float4*)(d + 4)  = *(const float4*)(s + 4);
    *(float4*)(d + 8)  = *(const float4*)(s + 8);
    *(float4*)(d + 12) = *(const float4*)(s + 12);
}

__device__ __forceinline__ void cvt16(half8& h0, half8& h1, const float* f) {
#pragma unroll
    for (int i = 0; i < 8; i++) { h0[i] = (_Float16)f[i]; h1[i] = (_Float16)f[8 + i]; }
}

// Fused Q/K/V projections: one launch, z selects input/weight/bias/output.
// C = A @ W^T + b, A fp32 [4096,1024], W fp32 [1024,1024]. 128x128 tile, BK=32,
// register-prefetch pipelined (T14): next-tile global loads issue before MFMA.
// z=0 -> Q (head-split [bh][l][d]), z=1 -> K (same), z=2 -> V transposed [bh][d][l].
__global__ __launch_bounds__(256) void gemm_qkv(
    const float* __restrict__ q, const float* __restrict__ k, const float* __restrict__ v,
    const float* __restrict__ Wq, const float* __restrict__ Wk, const float* __restrict__ Wv,
    const float* __restrict__ bq, const float* __restrict__ bk, const float* __restrict__ bv,
    _Float16* __restrict__ outQ, _Float16* __restrict__ outK, _Float16* __restrict__ outVt)
{
    __shared__ __align__(16) _Float16 sA[128 * 32];
    __shared__ __align__(16) _Float16 sB[128 * 32];

    const int t = threadIdx.x;
    const int tileN = blockIdx.x * 128;
    const int tileM = blockIdx.y * 128;
    const int z = blockIdx.z;

    const float* Ab = (z == 0) ? q : (z == 1 ? k : v);
    const float* Bb = (z == 0) ? Wq : (z == 1 ? Wk : Wv);
    const float* bias = (z == 0) ? bq : (z == 1 ? bk : bv);

    const int srow = t >> 1, shalf = t & 1, c0 = shalf * 2;
    const int lane = t & 63, wave = t >> 6;
    const int wm = (wave >> 1) * 64, wn = (wave & 1) * 64;
    const int l15 = lane & 15, quad = lane >> 4;

    const float* Arow = Ab + (long)(tileM + srow) * 1024 + shalf * 16;
    const float* Brow = Bb + (long)(tileN + srow) * 1024 + shalf * 16;

    float fA[16], fB[16];
    ld16f(fA, Arow);
    ld16f(fB, Brow);

    floatx4 acc[4][4];
#pragma unroll
    for (int i = 0; i < 4; i++)
#pragma unroll
        for (int j = 0; j < 4; j++)
            acc[i][j] = (floatx4){0.f, 0.f, 0.f, 0.f};

    for (int it = 0; it < 32; ++it) {
        __syncthreads();
        {
            half8 h0, h1;
            cvt16(h0, h1, fA);
            *(half8*)&sA[lds_off(srow, c0)]     = h0;
            *(half8*)&sA[lds_off(srow, c0 + 1)] = h1;
            cvt16(h0, h1, fB);
            *(half8*)&sB[lds_off(srow, c0)]     = h0;
            *(half8*)&sB[lds_off(srow, c0 + 1)] = h1;
        }
        __syncthreads();
        if (it + 1 < 32) {
            const int k1 = (it + 1) << 5;
            ld16f(fA, Arow + k1);
            ld16f(fB, Brow + k1);
        }
        half8 af[4], bf[4];
#pragma unroll
        for (int i = 0; i < 4; i++) af[i] = *(const half8*)&sA[lds_off(wm + i * 16 + l15, quad)];
#pragma unroll
        for (int j = 0; j < 4; j++) bf[j] = *(const half8*)&sB[lds_off(wn + j * 16 + l15, quad)];
#pragma unroll
        for (int i = 0; i < 4; i++)
#pragma unroll
            for (int j = 0; j < 4; j++)
                acc[i][j] = __builtin_amdgcn_mfma_f32_16x16x32_f16(af[i], bf[j], acc[i][j], 0, 0, 0);
    }

    // ---- epilogue ----
#pragma unroll
    for (int i = 0; i < 4; i++) {
#pragma unroll
        for (int j = 0; j < 4; j++) {
            const int row0 = tileM + wm + i * 16 + quad * 4;
            const int col  = tileN + wn + j * 16 + l15;
            if (z == 2) {
                half4 hv;
#pragma unroll
                for (int r = 0; r < 4; r++) hv[r] = (_Float16)(acc[i][j][r] + bias[col]);
                const int bh = ((row0 >> 11) << 4) + (col >> 6);
                *(half4*)&outVt[(long)bh * 131072 + (long)(col & 63) * 2048 + (row0 & 2047)] = hv;
            } else {
                _Float16* dst = z ? outK : outQ;
#pragma unroll
                for (int r = 0; r < 4; r++) {
                    const int row = row0 + r;
                    dst[(long)(((row >> 11) << 4) + (col >> 6)) * 131072 + (long)(row & 2047) * 64 + (col & 63)] =
                        (_Float16)(acc[i][j][r] + bias[col]);
                }
            }
        }
    }
}

// Output projection: C = A @ B^T + bias, A fp16 [4096,1024], B fp32 [1024,1024],
// C fp32 [4096,1024]. Same pipelined 128x128/BK=32 structure.
__global__ __launch_bounds__(256) void gemm_out(
    const _Float16* __restrict__ A, const float* __restrict__ B,
    const float* __restrict__ bias, float* __restrict__ C)
{
    __shared__ __align__(16) _Float16 sA[128 * 32];
    __shared__ __align__(16) _Float16 sB[128 * 32];

    const int t = threadIdx.x;
    const int tileN = blockIdx.x * 128;
    const int tileM = blockIdx.y * 128;

    const int srow = t >> 1, shalf = t & 1, c0 = shalf * 2;
    const int lane = t & 63, wave = t >> 6;
    const int wm = (wave >> 1) * 64, wn = (wave & 1) * 64;
    const int l15 = lane & 15, quad = lane >> 4;

    const _Float16* Arow = A + (long)(tileM + srow) * 1024 + shalf * 16;
    const float*    Brow = B + (long)(tileN + srow) * 1024 + shalf * 16;

    half8 hA[2];
    float fB[16];
    hA[0] = *(const half8*)Arow;
    hA[1] = *(const half8*)(Arow + 8);
    ld16f(fB, Brow);

    floatx4 acc[4][4];
#pragma unroll
    for (int i = 0; i < 4; i++)
#pragma unroll
        for (int j = 0; j < 4; j++)
            acc[i][j] = (floatx4){0.f, 0.f, 0.f, 0.f};

    for (int it = 0; it < 32; ++it) {
        __syncthreads();
        {
            *(half8*)&sA[lds_off(srow, c0)]     = hA[0];
            *(half8*)&sA[lds_off(srow, c0 + 1)] = hA[1];
            half8 h0, h1;
            cvt16(h0, h1, fB);
            *(half8*)&sB[lds_off(srow, c0)]     = h0;
            *(half8*)&sB[lds_off(srow, c0 + 1)] = h1;
        }
        __syncthreads();
        if (it + 1 < 32) {
            const int k1 = (it + 1) << 5;
            hA[0] = *(const half8*)(Arow + k1);
            hA[1] = *(const half8*)(Arow + k1 + 8);
            ld16f(fB, Brow + k1);
        }
        half8 af[4], bf[4];
#pragma unroll
        for (int i = 0; i < 4; i++) af[i] = *(const half8*)&sA[lds_off(wm + i * 16 + l15, quad)];
#pragma unroll
        for (int j = 0; j < 4; j++) bf[j] = *(const half8*)&sB[lds_off(wn + j * 16 + l15, quad)];
#pragma unroll
        for (int i = 0; i < 4; i++)
#pragma unroll
            for (int j = 0; j < 4; j++)
                acc[i][j] = __builtin_amdgcn_mfma_f32_16x16x32_f16(af[i], bf[j], acc[i][j], 0, 0, 0);
    }

#pragma unroll
    for (int i = 0; i < 4; i++)
#pragma unroll
        for (int j = 0; j < 4; j++)
#pragma unroll
            for (int r = 0; r < 4; r++) {
                const int row = tileM + wm + i * 16 + quad * 4 + r;
                const int col = tileN + wn + j * 16 + l15;
                C[(long)row * 1024 + col] = acc[i][j][r] + bias[col];
            }
}

// Fused attention: per (b,h) and 128-query-row block, two-pass flash-style with
// register-prefetch of the next K (pass 1) / K+V (pass 2) tiles under compute.
__global__ __launch_bounds__(256, 2) void attn_fused(
    const _Float16* __restrict__ Q,   // [32][2048][64]
    const _Float16* __restrict__ K,   // [32][2048][64]
    const _Float16* __restrict__ Vt,  // [32][64][2048]
    float* __restrict__ W,            // [32][2048][2048] (weights output)
    _Float16* __restrict__ Z)         // [4096][1024]  (b,l,h,d)
{
    __shared__ __align__(16) _Float16 sK[128 * 64];   // K tile  [128 key][64 d]
    __shared__ __align__(16) _Float16 sV[64 * 128];   // Vt tile [64 d][128 key]
    __shared__ __align__(16) _Float16 sP[128 * 128];  // P tile  [128 q][128 key]

    const int t = threadIdx.x;
    const int tileM = blockIdx.x * 128;
    const int bh = blockIdx.y;
    const int lane = t & 63, wave = t >> 6;
    const int l15 = lane & 15, quad = lane >> 4;
    const int wm = wave * 32;

    const _Float16* Qb = Q + (long)bh * 131072;
    const _Float16* Kb = K + (long)bh * 131072;
    const _Float16* Vb = Vt + (long)bh * 131072;
    float* Wb = W + (long)bh * 4194304;

    const int krow = t >> 1, khalf = t & 1;   // K staging: 2 threads/row, 64B each
    const int vrow = t >> 2, vq = t & 3;      // V staging: 4 threads/row

    // Q fragments (persistent): lane holds Q[row=wm+i*16+l15][k=kk*32+quad*8+e]
    half8 qf[2][2];
#pragma unroll
    for (int i = 0; i < 2; i++)
#pragma unroll
        for (int kk = 0; kk < 2; kk++)
            qf[i][kk] = *(const half8*)(Qb + (long)(tileM + wm + i * 16 + l15) * 64 + kk * 32 + quad * 8);

    float m[2][4], l[2][4];
#pragma unroll
    for (int i = 0; i < 2; i++)
#pragma unroll
        for (int r = 0; r < 4; r++) { m[i][r] = -__builtin_inff(); l[i][r] = 0.f; }

    const _Float16* Ksrc = Kb + (long)krow * 64 + khalf * 32;
    const _Float16* Vsrc = Vb + (long)vrow * 2048;

    half8 kr[4], vr[4];
#pragma unroll
    for (int c = 0; c < 4; c++) kr[c] = *(const half8*)(Ksrc + c * 8);

    // ---------------- pass 1: row stats ----------------
    for (int kv = 0; kv < 2048; kv += 128) {
        __syncthreads();
#pragma unroll
        for (int c = 0; c < 4; c++)
            *(half8*)&sK[krow * 64 + (((khalf * 4 + c) ^ (krow & 7)) << 3)] = kr[c];
        __syncthreads();
        if (kv + 128 < 2048) {
#pragma unroll
            for (int c = 0; c < 4; c++) kr[c] = *(const half8*)(Ksrc + (long)(kv + 128) * 64 + c * 8);
        }

        floatx4 acc[2][8];
#pragma unroll
        for (int i = 0; i < 2; i++)
#pragma unroll
            for (int j = 0; j < 8; j++) acc[i][j] = (floatx4){0.f, 0.f, 0.f, 0.f};

#pragma unroll
        for (int kk = 0; kk < 2; kk++) {
#pragma unroll
            for (int j = 0; j < 8; j++) {
                const int row = j * 16 + l15;
                half8 bf = *(const half8*)&sK[row * 64 + (((kk * 4 + quad) ^ (row & 7)) << 3)];
                acc[0][j] = __builtin_amdgcn_mfma_f32_16x16x32_f16(qf[0][kk], bf, acc[0][j], 0, 0, 0);
                acc[1][j] = __builtin_amdgcn_mfma_f32_16x16x32_f16(qf[1][kk], bf, acc[1][j], 0, 0, 0);
            }
        }

#pragma unroll
        for (int i = 0; i < 2; i++)
#pragma unroll
            for (int r = 0; r < 4; r++) {
                float tmax = acc[i][0][r];
#pragma unroll
                for (int j = 1; j < 8; j++) tmax = fmaxf(tmax, acc[i][j][r]);
#pragma unroll
                for (int off = 1; off < 16; off <<= 1) tmax = fmaxf(tmax, __shfl_xor(tmax, off));
                const float mn = fmaxf(m[i][r], tmax * 0.125f);
                const float corr = __expf(m[i][r] - mn);
                float ts = 0.f;
#pragma unroll
                for (int j = 0; j < 8; j++) ts += __expf(acc[i][j][r] * 0.125f - mn);
#pragma unroll
                for (int off = 1; off < 16; off <<= 1) ts += __shfl_xor(ts, off);
                l[i][r] = l[i][r] * corr + ts;
                m[i][r] = mn;
            }
    }

    // invert sums once
#pragma unroll
    for (int i = 0; i < 2; i++)
#pragma unroll
        for (int r = 0; r < 4; r++) l[i][r] = 1.f / l[i][r];

    floatx4 accz[2][4];
#pragma unroll
    for (int i = 0; i < 2; i++)
#pragma unroll
        for (int j = 0; j < 4; j++) accz[i][j] = (floatx4){0.f, 0.f, 0.f, 0.f};

    // reload tiles for kv=0 of pass 2
#pragma unroll
    for (int c = 0; c < 4; c++) kr[c] = *(const half8*)(Ksrc + c * 8);
#pragma unroll
    for (int c = 0; c < 4; c++) vr[c] = *(const half8*)(Vsrc + (vq + c * 4) * 8);

    // ---------------- pass 2: P write + PV ----------------
    for (int kv = 0; kv < 2048; kv += 128) {
        __syncthreads();
#pragma unroll
        for (int c = 0; c < 4; c++)
            *(half8*)&sK[krow * 64 + (((khalf * 4 + c) ^ (krow & 7)) << 3)] = kr[c];
#pragma unroll
        for (int c = 0; c < 4; c++) {
            const int ch = vq + c * 4;
            *(half8*)&sV[vrow * 128 + ((ch ^ (vrow & 15)) << 3)] = vr[c];
        }
        __syncthreads();
        if (kv + 128 < 2048) {
#pragma unroll
            for (int c = 0; c < 4; c++) kr[c] = *(const half8*)(Ksrc + (long)(kv + 128) * 64 + c * 8);
#pragma unroll
            for (int c = 0; c < 4; c++) vr[c] = *(const half8*)(Vsrc + kv + 128 + (vq + c * 4) * 8);
        }

        floatx4 acc[2][8];
#pragma unroll
        for (int i = 0; i < 2; i++)
#pragma unroll
            for (int j = 0; j < 8; j++) acc[i][j] = (floatx4){0.f, 0.f, 0.f, 0.f};

#pragma unroll
        for (int kk = 0; kk < 2; kk++) {
#pragma unroll
            for (int j = 0; j < 8; j++) {
                const int row = j * 16 + l15;
                half8 bf = *(const half8*)&sK[row * 64 + (((kk * 4 + quad) ^ (row & 7)) << 3)];
                acc[0][j] = __builtin_amdgcn_mfma_f32_16x16x32_f16(qf[0][kk], bf, acc[0][j], 0, 0, 0);
                acc[1][j] = __builtin_amdgcn_mfma_f32_16x16x32_f16(qf[1][kk], bf, acc[1][j], 0, 0, 0);
            }
        }

        // normalize, write weights (fp32, exactly once), stash fp16 P into LDS
#pragma unroll
        for (int i = 0; i < 2; i++) {
#pragma unroll
            for (int r = 0; r < 4; r++) {
                const int q = wm + i * 16 + quad * 4 + r;
                float* wr = Wb + (long)(tileM + q) * 2048 + kv + l15;
                _Float16* sprow = &sP[q * 128 + (l15 & 7)];
                const int qx = q & 15;
                const int hi = l15 >> 3;
#pragma unroll
                for (int j = 0; j < 8; j++) {
                    const float p = __expf(acc[i][j][r] * 0.125f - m[i][r]) * l[i][r];
                    __builtin_nontemporal_store(p, wr + j * 16);
                    sprow[((j * 2 + hi) ^ qx) << 3] = (_Float16)p;
                }
            }
        }
        __syncthreads();

        // Z += P @ Vt^T  (k-dim = 128 keys of this tile)
#pragma unroll
        for (int kk = 0; kk < 4; kk++) {
            half8 pf[2];
#pragma unroll
            for (int i = 0; i < 2; i++) {
                const int q = wm + i * 16 + l15;
                pf[i] = *(const half8*)&sP[q * 128 + (((kk * 4 + quad) ^ (q & 15)) << 3)];
            }
#pragma unroll
            for (int j = 0; j < 4; j++) {
                const int d = j * 16 + l15;
                half8 vf = *(const half8*)&sV[d * 128 + (((kk * 4 + quad) ^ (d & 15)) << 3)];
                accz[0][j] = __builtin_amdgcn_mfma_f32_16x16x32_f16(pf[0], vf, accz[0][j], 0, 0, 0);
                accz[1][j] = __builtin_amdgcn_mfma_f32_16x16x32_f16(pf[1], vf, accz[1][j], 0, 0, 0);
            }
        }
    }

    // ---- epilogue: Z to fp16 workspace [b*2048+l][h*64+d] ----
    const int bb = bh >> 4, hd = bh & 15;
#pragma unroll
    for (int i = 0; i < 2; i++)
#pragma unroll
        for (int j = 0; j < 4; j++)
#pragma unroll
            for (int r = 0; r < 4; r++)
                Z[(long)(bb * 2048 + tileM + wm + i * 16 + quad * 4 + r) * 1024 + hd * 64 + j * 16 + l15] =
                    (_Float16)accz[i][j][r];
}

extern "C" void kernel_launch(void* const* d_in, const int* in_sizes, int n_in,
                              void* d_out, int out_size, void* d_ws, size_t ws_size,
                              hipStream_t stream) {
    (void)in_sizes; (void)n_in; (void)out_size; (void)ws_size;
    const float* query = (const float*)d_in[0];
    const float* key   = (const float*)d_in[1];
    const float* value = (const float*)d_in[2];
    const float* Wq = (const float*)d_in[3];
    const float* bq = (const float*)d_in[4];
    const float* Wk = (const float*)d_in[5];
    const float* bk = (const float*)d_in[6];
    const float* Wv = (const float*)d_in[7];
    const float* bv = (const float*)d_in[8];
    const float* Wo = (const float*)d_in[9];
    const float* bo = (const float*)d_in[10];

    _Float16* wsQ  = (_Float16*)d_ws;        // [32][2048][64]
    _Float16* wsK  = wsQ + 4194304;          // [32][2048][64]
    _Float16* wsVt = wsK + 4194304;          // [32][64][2048]
    _Float16* wsZ  = wsVt + 4194304;         // [4096][1024]

    float* outF = (float*)d_out;             // [4096][1024]
    float* Wgt  = outF + 4194304;            // [32][2048][2048]

    dim3 blk(256);
    // Q/K/V projections fused into one launch (768 blocks = 3/CU)
    gemm_qkv<<<dim3(8, 32, 3), blk, 0, stream>>>(query, key, value, Wq, Wk, Wv, bq, bk, bv, wsQ, wsK, wsVt);
    // Fused scores + softmax + AV: writes weights once, Z to workspace
    attn_fused<<<dim3(16, 32), blk, 0, stream>>>(wsQ, wsK, wsVt, Wgt, wsZ);
    // out = Z Wo^T + bo
    gemm_out<<<dim3(8, 32), blk, 0, stream>>>(wsZ, Wo, bo, outF);
}